// Round 9
// baseline (212.544 us; speedup 1.0000x reference)
//
#include <hip/hip_runtime.h>
#include <cstdint>
#include <climits>

static constexpr int NC = 2000000;   // clause id range (fixed by reference)
static_assert(NC % 16 == 0, "check_k vector path needs NC % 16 == 0");

typedef int   int4v   __attribute__((ext_vector_type(4)));
typedef float float4v __attribute__((ext_vector_type(4)));

// ws layout (bytes)
static constexpr size_t OFF_FLAGS = 0;                       // u8 flags[NC] (shared)
static constexpr size_t FLAGS_BY  = (size_t)NC;              // 2,000,000
static constexpr size_t OFF_CNT   = OFF_FLAGS + FLAGS_BY;    // u32 counts[NC] (exact path)
static constexpr size_t CNT_BY    = (size_t)NC * 4;          // 8,000,000
static constexpr size_t OFF_XBB   = OFF_CNT + CNT_BY;        // bit-packed xb

// Zero flags, bit-pack xb (xb = floor(xv/0.50001f), true f32 divide to match
// the reference), init ctrl.
__global__ __launch_bounds__(256) void init_k(const float* __restrict__ xv, int nv,
                                              uint8_t* __restrict__ xbb,
                                              int4v* __restrict__ flags16,
                                              int* __restrict__ ctrl) {
    int stride = gridDim.x * blockDim.x;
    int i0 = blockIdx.x * blockDim.x + threadIdx.x;
    int nf16 = (int)(FLAGS_BY / 16);
    int4v z = {0, 0, 0, 0};
    for (int i = i0; i < nf16; i += stride) flags16[i] = z;
    int nbytes = nv >> 3;
    const float4v* p4 = (const float4v*)xv;
    for (int i = i0; i < nbytes; i += stride) {
        float4v a = p4[2 * i], b = p4[2 * i + 1];
        uint32_t m = 0;
        #pragma unroll
        for (int j = 0; j < 4; ++j)
            m |= ((uint32_t)(int)floorf(a[j] / 0.50001f)) << j;
        #pragma unroll
        for (int j = 0; j < 4; ++j)
            m |= ((uint32_t)(int)floorf(b[j] / 0.50001f)) << (4 + j);
        xbb[i] = (uint8_t)m;
    }
    if (i0 == 0) {
        if (nv & 7) {
            uint32_t m = 0;
            for (int j = 0; j < (nv & 7); ++j)
                m |= ((uint32_t)(int)floorf(xv[(nbytes << 3) + j] / 0.50001f)) << j;
            xbb[nbytes] = (uint8_t)m;
        }
        ctrl[0] = 0;        // zero_found
        ctrl[1] = INT_MAX;  // minslot (exact path)
    }
}

// Flag pass: per satisfied edge, test-before-set a shared byte flag.
// Plain stores only (idempotent value 1); L2 dirty-byte masks make cross-XCD
// line merge safe (evidence: no fetch-on-write in round-8 counters).
// Test-first keeps evicted lines CLEAN on re-touch -> one writeback per line.
__global__ __launch_bounds__(256) void flag_k(const int* __restrict__ adj_pos,
                                              const int* __restrict__ adj_neg,
                                              const uint32_t* __restrict__ xbw,
                                              uint8_t* __restrict__ flags,
                                              int ne_p, int ne_n) {
    int gid = blockIdx.x * 256 + threadIdx.x;
    int gstride = gridDim.x * 256;

    const int* adjs[2] = {adj_pos, adj_neg};
    int nes[2] = {ne_p, ne_n};
    for (int pol = 0; pol < 2; ++pol) {
        const int* adj = adjs[pol];
        int ne = nes[pol];
        int neg = pol;
        int n4 = ((ne & 3) == 0) ? (ne >> 2) : 0;   // vector path needs aligned rows
        const int4v* c4 = (const int4v*)adj;
        const int4v* v4 = (const int4v*)(adj + ne);
        for (int i = gid; i < n4; i += gstride) {
            int4v c = __builtin_nontemporal_load(c4 + i);
            int4v v = __builtin_nontemporal_load(v4 + i);
            #pragma unroll
            for (int j = 0; j < 4; ++j) {
                int cc = c[j], vv = v[j];
                int bit = (int)((xbw[vv >> 5] >> (vv & 31)) & 1u);
                if (bit != neg && !flags[cc]) flags[cc] = (uint8_t)1;
            }
        }
        for (int e = (n4 << 2) + gid; e < ne; e += gstride) {   // scalar tail
            int cc = adj[e], vv = adj[ne + e];
            int bit = (int)((xbw[vv >> 5] >> (vv & 31)) & 1u);
            if (bit != neg && !flags[cc]) flags[cc] = (uint8_t)1;
        }
    }
}

// Check pass: any zero byte in flags[0, NC) => some clause has zero satisfied
// literals => min == 0.
__global__ __launch_bounds__(256) void check_k(const uint8_t* __restrict__ flags,
                                               int* __restrict__ zero_found) {
    int i = blockIdx.x * blockDim.x + threadIdx.x;
    int n16 = NC / 16;
    uint32_t z = 0;
    if (i < n16) {
        const int4v* f = (const int4v*)flags;
        int4v w = f[i];
        #pragma unroll
        for (int j = 0; j < 4; ++j) {
            uint32_t u = (uint32_t)w[j];
            z |= (u - 0x01010101u) & ~u & 0x80808080u;   // any-zero-byte test
        }
    }
    if (__any(z != 0) && (threadIdx.x & 63) == 0) atomicOr(zero_found, 1);
}

// ---- exact-count path (launched every call; early-exits when zero_found) ----
__global__ __launch_bounds__(256) void fbz_k(uint32_t* __restrict__ counts,
                                             const int* __restrict__ zf) {
    if (*zf) return;
    int stride = gridDim.x * blockDim.x;
    for (int i = blockIdx.x * blockDim.x + threadIdx.x; i < NC; i += stride)
        counts[i] = 0u;
}

template<int NEG>
__global__ __launch_bounds__(256) void fb_edge_k(const int* __restrict__ adj,
                                                 const uint32_t* __restrict__ xbw,
                                                 uint32_t* __restrict__ counts,
                                                 int ne, const int* __restrict__ zf) {
    if (*zf) return;
    int stride = gridDim.x * blockDim.x;
    int i0 = blockIdx.x * blockDim.x + threadIdx.x;
    for (int e = i0; e < ne; e += stride) {
        int c = adj[e];
        int v = adj[ne + e];
        int bit = (int)((xbw[v >> 5] >> (v & 31)) & 1u);
        if (bit != NEG) atomicAdd(&counts[c], 1u);
    }
}

__global__ __launch_bounds__(256) void fb_min_k(const uint32_t* __restrict__ counts,
                                                int* __restrict__ minslot,
                                                const int* __restrict__ zf) {
    if (*zf) return;
    int stride = gridDim.x * blockDim.x;
    int i0 = blockIdx.x * blockDim.x + threadIdx.x;
    int lo = INT_MAX;
    for (int i = i0; i < NC; i += stride) lo = min(lo, (int)counts[i]);
    for (int off = 32; off > 0; off >>= 1) lo = min(lo, __shfl_down(lo, off));
    if ((threadIdx.x & 63) == 0) atomicMin(minslot, lo);
}

__global__ void fin_k(const int* __restrict__ ctrl, float* __restrict__ out) {
    out[0] = ctrl[0] ? 0.0f : (float)ctrl[1];
}

extern "C" void kernel_launch(void* const* d_in, const int* in_sizes, int n_in,
                              void* d_out, int out_size, void* d_ws, size_t ws_size,
                              hipStream_t stream) {
    const float* xv    = (const float*)d_in[0];
    const int* adj_pos = (const int*)d_in[1];   // int32 per harness contract
    const int* adj_neg = (const int*)d_in[2];
    float* out = (float*)d_out;

    const int nv   = in_sizes[0];
    const int ne_p = in_sizes[1] / 2;   // rows: [clause, var]
    const int ne_n = in_sizes[2] / 2;

    char* ws = (char*)d_ws;
    dim3 blk(256);

    const size_t xbb_by  = (((size_t)nv + 7) / 8 + 64) & ~63ull;
    const size_t off_ctl = OFF_XBB + xbb_by;
    const size_t need    = off_ctl + 64;

    if (ws_size >= need) {
        uint8_t*  flags = (uint8_t*) (ws + OFF_FLAGS);
        uint32_t* cnts  = (uint32_t*)(ws + OFF_CNT);
        uint8_t*  xbb   = (uint8_t*) (ws + OFF_XBB);
        int*      ctrl  = (int*)     (ws + off_ctl);   // [0]=zero_found [1]=minslot
        const uint32_t* xbw = (const uint32_t*)xbb;

        init_k<<<2048, blk, 0, stream>>>(xv, nv, xbb, (int4v*)flags, ctrl);
        flag_k<<<1024, blk, 0, stream>>>(adj_pos, adj_neg, xbw, flags, ne_p, ne_n);
        check_k<<<(NC / 16 + 255) / 256, blk, 0, stream>>>(flags, ctrl);
        // Exact path: launched every call, early-exits when a zero clause exists.
        fbz_k<<<2048, blk, 0, stream>>>(cnts, ctrl);
        fb_edge_k<0><<<2048, blk, 0, stream>>>(adj_pos, xbw, cnts, ne_p, ctrl);
        fb_edge_k<1><<<2048, blk, 0, stream>>>(adj_neg, xbw, cnts, ne_n, ctrl);
        fb_min_k<<<2048, blk, 0, stream>>>(cnts, ctrl + 1, ctrl);
        fin_k<<<1, 1, 0, stream>>>(ctrl, out);
    } else {
        // Minimal-ws fallback: exact path only (ungated).
        uint32_t* cnts = (uint32_t*)ws;
        uint8_t*  xbb  = (uint8_t*) (ws + CNT_BY);
        int*      ctrl = (int*)     (ws + CNT_BY + xbb_by);
        const uint32_t* xbw = (const uint32_t*)xbb;
        init_k<<<2048, blk, 0, stream>>>(xv, nv, xbb, (int4v*)cnts /*scratch*/, ctrl);
        fbz_k<<<2048, blk, 0, stream>>>(cnts, ctrl);            // ctrl[0]==0 -> runs
        fb_edge_k<0><<<2048, blk, 0, stream>>>(adj_pos, xbw, cnts, ne_p, ctrl);
        fb_edge_k<1><<<2048, blk, 0, stream>>>(adj_neg, xbw, cnts, ne_n, ctrl);
        fb_min_k<<<2048, blk, 0, stream>>>(cnts, ctrl + 1, ctrl);
        fin_k<<<1, 1, 0, stream>>>(ctrl, out);
    }
}

// Round 10
// 165.278 us; speedup vs baseline: 1.2860x; 1.2860x over previous
//
#include <hip/hip_runtime.h>
#include <cstdint>
#include <climits>

static constexpr int NC = 2000000;   // clause id range (fixed by reference)
static_assert(NC % 16 == 0, "check_k vector path needs NC % 16 == 0");

typedef int   int4v   __attribute__((ext_vector_type(4)));
typedef float float4v __attribute__((ext_vector_type(4)));

// ws layout (bytes)
static constexpr size_t OFF_FLAGS = 0;                       // u8 flags[NC] (shared)
static constexpr size_t FLAGS_BY  = (size_t)NC;              // 2,000,000
static constexpr size_t OFF_CNT   = OFF_FLAGS + FLAGS_BY;    // u32 counts[NC] (exact path)
static constexpr size_t CNT_BY    = (size_t)NC * 4;          // 8,000,000
static constexpr size_t OFF_XBB   = OFF_CNT + CNT_BY;        // bit-packed xb

// Zero flags, bit-pack xb (xb = floor(xv/0.50001f), true f32 divide to match
// the reference), init ctrl.
__global__ __launch_bounds__(256) void init_k(const float* __restrict__ xv, int nv,
                                              uint8_t* __restrict__ xbb,
                                              int4v* __restrict__ flags16,
                                              int* __restrict__ ctrl) {
    int stride = gridDim.x * blockDim.x;
    int i0 = blockIdx.x * blockDim.x + threadIdx.x;
    int nf16 = (int)(FLAGS_BY / 16);
    int4v z = {0, 0, 0, 0};
    for (int i = i0; i < nf16; i += stride) flags16[i] = z;
    int nbytes = nv >> 3;
    const float4v* p4 = (const float4v*)xv;
    for (int i = i0; i < nbytes; i += stride) {
        float4v a = p4[2 * i], b = p4[2 * i + 1];
        uint32_t m = 0;
        #pragma unroll
        for (int j = 0; j < 4; ++j)
            m |= ((uint32_t)(int)floorf(a[j] / 0.50001f)) << j;
        #pragma unroll
        for (int j = 0; j < 4; ++j)
            m |= ((uint32_t)(int)floorf(b[j] / 0.50001f)) << (4 + j);
        xbb[i] = (uint8_t)m;
    }
    if (i0 == 0) {
        if (nv & 7) {
            uint32_t m = 0;
            for (int j = 0; j < (nv & 7); ++j)
                m |= ((uint32_t)(int)floorf(xv[(nbytes << 3) + j] / 0.50001f)) << j;
            xbb[nbytes] = (uint8_t)m;
        }
        ctrl[0] = 0;        // zero_found
        ctrl[1] = INT_MAX;  // minslot (exact path)
    }
}

// Flag pass, ILP-unrolled x4: per iteration each thread issues 8 streaming
// int4 loads (16 edges) + 16 independent bit gathers before any use ->
// ~24 loads in flight per thread, hiding the L2/L3 latency chain that
// bounded round 8 (6 cyc/edge, VALU 2.6%). Write-only idempotent byte
// stores into ONE shared flag array (cross-XCD dirty-byte merge proven
// safe by rounds 8/9: no fetch-on-write, absmax 0).
__global__ __launch_bounds__(256) void flag_k(const int* __restrict__ adj_pos,
                                              const int* __restrict__ adj_neg,
                                              const uint32_t* __restrict__ xbw,
                                              uint8_t* __restrict__ flags,
                                              int ne_p, int ne_n) {
    int gid = blockIdx.x * 256 + threadIdx.x;
    int gstride = gridDim.x * 256;

    const int* adjs[2] = {adj_pos, adj_neg};
    int nes[2] = {ne_p, ne_n};
    for (int pol = 0; pol < 2; ++pol) {
        const int* adj = adjs[pol];
        int ne = nes[pol];
        int neg = pol;
        int n16 = ((ne & 3) == 0) ? (ne >> 4) : 0;   // groups of 16 edges
        const int4v* c4 = (const int4v*)adj;
        const int4v* v4 = (const int4v*)(adj + ne);
        for (int g = gid; g < n16; g += gstride) {
            int4v c[4], v[4];
            #pragma unroll
            for (int u = 0; u < 4; ++u) {
                c[u] = __builtin_nontemporal_load(c4 + 4 * g + u);
                v[u] = __builtin_nontemporal_load(v4 + 4 * g + u);
            }
            uint32_t bit[4][4];
            #pragma unroll
            for (int u = 0; u < 4; ++u)
                #pragma unroll
                for (int j = 0; j < 4; ++j) {
                    int vv = v[u][j];
                    bit[u][j] = (xbw[vv >> 5] >> (vv & 31)) & 1u;
                }
            #pragma unroll
            for (int u = 0; u < 4; ++u)
                #pragma unroll
                for (int j = 0; j < 4; ++j)
                    if ((int)bit[u][j] != neg) flags[c[u][j]] = (uint8_t)1;
        }
        for (int e = (n16 << 4) + gid; e < ne; e += gstride) {   // tail
            int cc = adj[e], vv = adj[ne + e];
            int b = (int)((xbw[vv >> 5] >> (vv & 31)) & 1u);
            if (b != neg) flags[cc] = (uint8_t)1;
        }
    }
}

// Check pass: any zero byte in flags[0, NC) => some clause has zero satisfied
// literals => min == 0.
__global__ __launch_bounds__(256) void check_k(const uint8_t* __restrict__ flags,
                                               int* __restrict__ zero_found) {
    int i = blockIdx.x * blockDim.x + threadIdx.x;
    int n16 = NC / 16;
    uint32_t z = 0;
    if (i < n16) {
        const int4v* f = (const int4v*)flags;
        int4v w = f[i];
        #pragma unroll
        for (int j = 0; j < 4; ++j) {
            uint32_t u = (uint32_t)w[j];
            z |= (u - 0x01010101u) & ~u & 0x80808080u;   // any-zero-byte test
        }
    }
    if (__any(z != 0) && (threadIdx.x & 63) == 0) atomicOr(zero_found, 1);
}

// ---- exact-count path (launched every call; early-exits when zero_found) ----
__global__ __launch_bounds__(256) void fbz_k(uint32_t* __restrict__ counts,
                                             const int* __restrict__ zf) {
    if (*zf) return;
    int stride = gridDim.x * blockDim.x;
    for (int i = blockIdx.x * blockDim.x + threadIdx.x; i < NC; i += stride)
        counts[i] = 0u;
}

template<int NEG>
__global__ __launch_bounds__(256) void fb_edge_k(const int* __restrict__ adj,
                                                 const uint32_t* __restrict__ xbw,
                                                 uint32_t* __restrict__ counts,
                                                 int ne, const int* __restrict__ zf) {
    if (*zf) return;
    int stride = gridDim.x * blockDim.x;
    int i0 = blockIdx.x * blockDim.x + threadIdx.x;
    for (int e = i0; e < ne; e += stride) {
        int c = adj[e];
        int v = adj[ne + e];
        int bit = (int)((xbw[v >> 5] >> (v & 31)) & 1u);
        if (bit != NEG) atomicAdd(&counts[c], 1u);
    }
}

__global__ __launch_bounds__(256) void fb_min_k(const uint32_t* __restrict__ counts,
                                                int* __restrict__ minslot,
                                                const int* __restrict__ zf) {
    if (*zf) return;
    int stride = gridDim.x * blockDim.x;
    int i0 = blockIdx.x * blockDim.x + threadIdx.x;
    int lo = INT_MAX;
    for (int i = i0; i < NC; i += stride) lo = min(lo, (int)counts[i]);
    for (int off = 32; off > 0; off >>= 1) lo = min(lo, __shfl_down(lo, off));
    if ((threadIdx.x & 63) == 0) atomicMin(minslot, lo);
}

__global__ void fin_k(const int* __restrict__ ctrl, float* __restrict__ out) {
    out[0] = ctrl[0] ? 0.0f : (float)ctrl[1];
}

extern "C" void kernel_launch(void* const* d_in, const int* in_sizes, int n_in,
                              void* d_out, int out_size, void* d_ws, size_t ws_size,
                              hipStream_t stream) {
    const float* xv    = (const float*)d_in[0];
    const int* adj_pos = (const int*)d_in[1];   // int32 per harness contract
    const int* adj_neg = (const int*)d_in[2];
    float* out = (float*)d_out;

    const int nv   = in_sizes[0];
    const int ne_p = in_sizes[1] / 2;   // rows: [clause, var]
    const int ne_n = in_sizes[2] / 2;

    char* ws = (char*)d_ws;
    dim3 blk(256);

    const size_t xbb_by  = (((size_t)nv + 7) / 8 + 64) & ~63ull;
    const size_t off_ctl = OFF_XBB + xbb_by;
    const size_t need    = off_ctl + 64;

    if (ws_size >= need) {
        uint8_t*  flags = (uint8_t*) (ws + OFF_FLAGS);
        uint32_t* cnts  = (uint32_t*)(ws + OFF_CNT);
        uint8_t*  xbb   = (uint8_t*) (ws + OFF_XBB);
        int*      ctrl  = (int*)     (ws + off_ctl);   // [0]=zero_found [1]=minslot
        const uint32_t* xbw = (const uint32_t*)xbb;

        init_k<<<2048, blk, 0, stream>>>(xv, nv, xbb, (int4v*)flags, ctrl);
        flag_k<<<2048, blk, 0, stream>>>(adj_pos, adj_neg, xbw, flags, ne_p, ne_n);
        check_k<<<(NC / 16 + 255) / 256, blk, 0, stream>>>(flags, ctrl);
        // Exact path: launched every call, early-exits when a zero clause exists.
        fbz_k<<<2048, blk, 0, stream>>>(cnts, ctrl);
        fb_edge_k<0><<<2048, blk, 0, stream>>>(adj_pos, xbw, cnts, ne_p, ctrl);
        fb_edge_k<1><<<2048, blk, 0, stream>>>(adj_neg, xbw, cnts, ne_n, ctrl);
        fb_min_k<<<2048, blk, 0, stream>>>(cnts, ctrl + 1, ctrl);
        fin_k<<<1, 1, 0, stream>>>(ctrl, out);
    } else {
        // Minimal-ws fallback: exact path only (ungated).
        uint32_t* cnts = (uint32_t*)ws;
        uint8_t*  xbb  = (uint8_t*) (ws + CNT_BY);
        int*      ctrl = (int*)     (ws + CNT_BY + xbb_by);
        const uint32_t* xbw = (const uint32_t*)xbb;
        init_k<<<2048, blk, 0, stream>>>(xv, nv, xbb, (int4v*)cnts /*scratch*/, ctrl);
        fbz_k<<<2048, blk, 0, stream>>>(cnts, ctrl);            // ctrl[0]==0 -> runs
        fb_edge_k<0><<<2048, blk, 0, stream>>>(adj_pos, xbw, cnts, ne_p, ctrl);
        fb_edge_k<1><<<2048, blk, 0, stream>>>(adj_neg, xbw, cnts, ne_n, ctrl);
        fb_min_k<<<2048, blk, 0, stream>>>(cnts, ctrl + 1, ctrl);
        fin_k<<<1, 1, 0, stream>>>(ctrl, out);
    }
}

// Round 11
// 129.867 us; speedup vs baseline: 1.6366x; 1.2727x over previous
//
#include <hip/hip_runtime.h>
#include <cstdint>
#include <climits>

static constexpr int NC   = 2000000;          // clause id range (fixed by reference)
static constexpr int HALF = 1000000;          // clauses per half-range
static constexpr int NBH  = 128;              // blocks per half
static constexpr int NBLK = 2 * NBH;          // 256 bitmap blocks (1 per CU)
static constexpr int WPH  = HALF / 32;        // 31,250 valid words per bitmap
static constexpr int LDSW = 31264;            // alloc words (pad to /4, zeroed)
static_assert(HALF % 32 == 0 && LDSW % 4 == 0 && LDSW >= WPH, "layout");

typedef int   int4v   __attribute__((ext_vector_type(4)));
typedef float float4v __attribute__((ext_vector_type(4)));

// ws layout (bytes). counts[] for the exact path ALIASES the bitmap region
// (bitmaps are dead after reduce_k; stream order serializes the reuse).
static constexpr size_t OFF_BM  = 0;
static constexpr size_t BM_BY   = (size_t)NBLK * LDSW * 4;   // 32,014,336
static constexpr size_t OFF_CNT = 0;                          // alias (8 MB)
static constexpr size_t OFF_XBB = BM_BY;                      // bit-packed xb

// Pack xb bits (xb = floor(xv/0.50001f), true f32 divide to match reference),
// init ctrl. No flag/bitmap zeroing needed (LDS zeroed in-kernel, regions
// fully overwritten by flush).
__global__ __launch_bounds__(256) void init_k(const float* __restrict__ xv, int nv,
                                              uint8_t* __restrict__ xbb,
                                              int* __restrict__ ctrl) {
    int stride = gridDim.x * blockDim.x;
    int i0 = blockIdx.x * blockDim.x + threadIdx.x;
    int nbytes = nv >> 3;
    const float4v* p4 = (const float4v*)xv;
    for (int i = i0; i < nbytes; i += stride) {
        float4v a = p4[2 * i], b = p4[2 * i + 1];
        uint32_t m = 0;
        #pragma unroll
        for (int j = 0; j < 4; ++j)
            m |= ((uint32_t)(int)floorf(a[j] / 0.50001f)) << j;
        #pragma unroll
        for (int j = 0; j < 4; ++j)
            m |= ((uint32_t)(int)floorf(b[j] / 0.50001f)) << (4 + j);
        xbb[i] = (uint8_t)m;
    }
    if (i0 == 0) {
        if (nv & 7) {
            uint32_t m = 0;
            for (int j = 0; j < (nv & 7); ++j)
                m |= ((uint32_t)(int)floorf(xv[(nbytes << 3) + j] / 0.50001f)) << j;
            xbb[nbytes] = (uint8_t)m;
        }
        ctrl[0] = 0;        // zero_found
        ctrl[1] = INT_MAX;  // minslot (exact path)
    }
}

// Bitmap pass: block (h,b) owns clause half h and edge share b. All scatter
// lands in a private 125 KB LDS bitmap via fire-and-forget ds_or; the only
// global writes are the dense nt flush (125 KB/block). Streaming int4 reads
// of both adjacency rows, xb-bit gather only for in-range edges.
__global__ __launch_bounds__(1024) void bitmap_k(const int* __restrict__ adj_pos,
                                                 const int* __restrict__ adj_neg,
                                                 const uint32_t* __restrict__ xbw,
                                                 uint32_t* __restrict__ regions,
                                                 int ne_p, int ne_n) {
    __shared__ uint32_t bm[LDSW];   // 125,056 B
    const int tid = threadIdx.x;
    for (int i = tid; i < LDSW; i += 1024) bm[i] = 0u;
    __syncthreads();

    const int h = blockIdx.x & 1;
    const int b = blockIdx.x >> 1;
    const uint32_t base = (uint32_t)(h * HALF);
    const int w = b * 1024 + tid;          // worker id within half
    const int W = NBH * 1024;              // 131,072 workers per half

    const int* adjs[2] = {adj_pos, adj_neg};
    int nes[2] = {ne_p, ne_n};
    for (int pol = 0; pol < 2; ++pol) {
        const int* adj = adjs[pol];
        const int ne = nes[pol];
        const int neg = pol;
        const int n4 = ((ne & 3) == 0) ? (ne >> 2) : 0;   // aligned vector path
        const int4v* c4p = (const int4v*)adj;
        const int4v* v4p = (const int4v*)(adj + ne);
        int i = w;
        for (; i + W < n4; i += 2 * W) {    // 2-deep ILP
            int4v c0 = __builtin_nontemporal_load(c4p + i);
            int4v v0 = __builtin_nontemporal_load(v4p + i);
            int4v c1 = __builtin_nontemporal_load(c4p + i + W);
            int4v v1 = __builtin_nontemporal_load(v4p + i + W);
            #pragma unroll
            for (int j = 0; j < 4; ++j) {
                uint32_t idx = (uint32_t)c0[j] - base;
                if (idx < (uint32_t)HALF) {
                    int vv = v0[j];
                    int bit = (int)((xbw[vv >> 5] >> (vv & 31)) & 1u);
                    if (bit != neg) atomicOr(&bm[idx >> 5], 1u << (idx & 31));
                }
            }
            #pragma unroll
            for (int j = 0; j < 4; ++j) {
                uint32_t idx = (uint32_t)c1[j] - base;
                if (idx < (uint32_t)HALF) {
                    int vv = v1[j];
                    int bit = (int)((xbw[vv >> 5] >> (vv & 31)) & 1u);
                    if (bit != neg) atomicOr(&bm[idx >> 5], 1u << (idx & 31));
                }
            }
        }
        for (; i < n4; i += W) {
            int4v c = __builtin_nontemporal_load(c4p + i);
            int4v v = __builtin_nontemporal_load(v4p + i);
            #pragma unroll
            for (int j = 0; j < 4; ++j) {
                uint32_t idx = (uint32_t)c[j] - base;
                if (idx < (uint32_t)HALF) {
                    int vv = v[j];
                    int bit = (int)((xbw[vv >> 5] >> (vv & 31)) & 1u);
                    if (bit != neg) atomicOr(&bm[idx >> 5], 1u << (idx & 31));
                }
            }
        }
        for (int e = (n4 << 2) + w; e < ne; e += W) {   // scalar tail
            uint32_t idx = (uint32_t)adj[e] - base;
            if (idx < (uint32_t)HALF) {
                int vv = adj[ne + e];
                int bit = (int)((xbw[vv >> 5] >> (vv & 31)) & 1u);
                if (bit != neg) atomicOr(&bm[idx >> 5], 1u << (idx & 31));
            }
        }
    }
    __syncthreads();

    // Dense flush (nt -> straight to HBM, full lines).
    int4v* dst = (int4v*)(regions + (size_t)blockIdx.x * LDSW);
    const int4v* src = (const int4v*)bm;
    for (int i = tid; i < LDSW / 4; i += 1024)
        __builtin_nontemporal_store(src[i], dst + i);
}

// OR the 128 bitmaps of each half per word; a 0 bit anywhere => some clause
// has zero satisfied literals => min == 0.
__global__ __launch_bounds__(256) void reduce_k(const uint32_t* __restrict__ regions,
                                                int* __restrict__ zero_found) {
    int gw = blockIdx.x * 256 + threadIdx.x;   // [0, 2*WPH)
    if (gw >= 2 * WPH) return;
    int h = (gw >= WPH) ? 1 : 0;
    int wd = gw - h * WPH;
    const uint32_t* p = regions + (size_t)h * LDSW + wd;   // region id = 2r+h
    uint32_t o0 = 0, o1 = 0, o2 = 0, o3 = 0;
    for (int r = 0; r < NBH; r += 4) {
        o0 |= p[(size_t)(r + 0) * 2 * LDSW];
        o1 |= p[(size_t)(r + 1) * 2 * LDSW];
        o2 |= p[(size_t)(r + 2) * 2 * LDSW];
        o3 |= p[(size_t)(r + 3) * 2 * LDSW];
    }
    uint32_t acc = (o0 | o1) | (o2 | o3);
    if (acc != 0xFFFFFFFFu) atomicOr(zero_found, 1);
}

// ---- exact-count path (launched every call; early-exits when zero_found) ----
__global__ __launch_bounds__(256) void fbz_k(uint32_t* __restrict__ counts,
                                             const int* __restrict__ zf) {
    if (*zf) return;
    int stride = gridDim.x * blockDim.x;
    for (int i = blockIdx.x * blockDim.x + threadIdx.x; i < NC; i += stride)
        counts[i] = 0u;
}

template<int NEG>
__global__ __launch_bounds__(256) void fb_edge_k(const int* __restrict__ adj,
                                                 const uint32_t* __restrict__ xbw,
                                                 uint32_t* __restrict__ counts,
                                                 int ne, const int* __restrict__ zf) {
    if (*zf) return;
    int stride = gridDim.x * blockDim.x;
    int i0 = blockIdx.x * blockDim.x + threadIdx.x;
    for (int e = i0; e < ne; e += stride) {
        int c = adj[e];
        int v = adj[ne + e];
        int bit = (int)((xbw[v >> 5] >> (v & 31)) & 1u);
        if (bit != NEG) atomicAdd(&counts[c], 1u);
    }
}

__global__ __launch_bounds__(256) void fb_min_k(const uint32_t* __restrict__ counts,
                                                int* __restrict__ minslot,
                                                const int* __restrict__ zf) {
    if (*zf) return;
    int stride = gridDim.x * blockDim.x;
    int i0 = blockIdx.x * blockDim.x + threadIdx.x;
    int lo = INT_MAX;
    for (int i = i0; i < NC; i += stride) lo = min(lo, (int)counts[i]);
    for (int off = 32; off > 0; off >>= 1) lo = min(lo, __shfl_down(lo, off));
    if ((threadIdx.x & 63) == 0) atomicMin(minslot, lo);
}

__global__ void fin_k(const int* __restrict__ ctrl, float* __restrict__ out) {
    out[0] = ctrl[0] ? 0.0f : (float)ctrl[1];
}

extern "C" void kernel_launch(void* const* d_in, const int* in_sizes, int n_in,
                              void* d_out, int out_size, void* d_ws, size_t ws_size,
                              hipStream_t stream) {
    const float* xv    = (const float*)d_in[0];
    const int* adj_pos = (const int*)d_in[1];   // int32 per harness contract
    const int* adj_neg = (const int*)d_in[2];
    float* out = (float*)d_out;

    const int nv   = in_sizes[0];
    const int ne_p = in_sizes[1] / 2;   // rows: [clause, var]
    const int ne_n = in_sizes[2] / 2;

    char* ws = (char*)d_ws;
    dim3 blk(256);

    const size_t xbb_by  = (((size_t)nv + 7) / 8 + 64) & ~63ull;
    const size_t off_ctl = OFF_XBB + xbb_by;
    const size_t need    = off_ctl + 64;

    if (ws_size >= need) {
        uint32_t* rgn  = (uint32_t*)(ws + OFF_BM);
        uint32_t* cnts = (uint32_t*)(ws + OFF_CNT);   // aliases rgn (dead after reduce)
        uint8_t*  xbb  = (uint8_t*) (ws + OFF_XBB);
        int*      ctrl = (int*)     (ws + off_ctl);   // [0]=zero_found [1]=minslot
        const uint32_t* xbw = (const uint32_t*)xbb;

        init_k<<<512, blk, 0, stream>>>(xv, nv, xbb, ctrl);
        bitmap_k<<<NBLK, dim3(1024), 0, stream>>>(adj_pos, adj_neg, xbw, rgn, ne_p, ne_n);
        reduce_k<<<(2 * WPH + 255) / 256, blk, 0, stream>>>(rgn, ctrl);
        // Exact path: launched every call, early-exits when a zero clause exists.
        fbz_k<<<2048, blk, 0, stream>>>(cnts, ctrl);
        fb_edge_k<0><<<2048, blk, 0, stream>>>(adj_pos, xbw, cnts, ne_p, ctrl);
        fb_edge_k<1><<<2048, blk, 0, stream>>>(adj_neg, xbw, cnts, ne_n, ctrl);
        fb_min_k<<<2048, blk, 0, stream>>>(cnts, ctrl + 1, ctrl);
        fin_k<<<1, 1, 0, stream>>>(ctrl, out);
    } else {
        // Minimal-ws fallback: exact path only (ungated).
        const size_t cnt_by = (size_t)NC * 4;
        uint32_t* cnts = (uint32_t*)ws;
        uint8_t*  xbb  = (uint8_t*) (ws + cnt_by);
        int*      ctrl = (int*)     (ws + cnt_by + xbb_by);
        const uint32_t* xbw = (const uint32_t*)xbb;
        init_k<<<512, blk, 0, stream>>>(xv, nv, xbb, ctrl);
        fbz_k<<<2048, blk, 0, stream>>>(cnts, ctrl);            // ctrl[0]==0 -> runs
        fb_edge_k<0><<<2048, blk, 0, stream>>>(adj_pos, xbw, cnts, ne_p, ctrl);
        fb_edge_k<1><<<2048, blk, 0, stream>>>(adj_neg, xbw, cnts, ne_n, ctrl);
        fb_min_k<<<2048, blk, 0, stream>>>(cnts, ctrl + 1, ctrl);
        fin_k<<<1, 1, 0, stream>>>(ctrl, out);
    }
}